// Round 4
// baseline (116.572 us; speedup 1.0000x reference)
//
#include <hip/hip_runtime.h>
#include <stdint.h>

// ---------------------------------------------------------------------------
// CritiGraph distance kernel: bit-exact reproduction of the JAX reference
// (jax_threefry_partitionable=True path, verified absmax 0.0 rounds 1-3).
//
// Round-4 structure:
//   - Compile-time permutation (constexpr threefry + chunked stable-rank)
//     in __constant__ memory; single kernel launch.
//   - dist_kernel: one thread per (t,tp), 8 j-values per thread (h is
//     block-uniform: j = 8*jg..8*jg+7 never crosses a multiple of 16).
//     8 independent threefry chains for ILP; ori/norm gather amortized
//     over 16 stores.
//   - Proven simplifications (bit-exact):
//       * sign(v)==sign(ori) always (v^ori = fm < 2^16, bit31 untouched)
//         -> d1 needs no sign logic; d2 = (v==0) ? d1 : -d1.
//       * |ori| loop-invariant, hoisted.
//       * f = nm*(1-(32-lz)/16) == fma(lz, nm/16, -nm): nm/16 exact
//         (2^-4 scale), fma single-rounding == reference single-rounding.
// ---------------------------------------------------------------------------

#define H_   16
#define TP_  16
#define K_   16
#define T_   2048
#define NC   513                       // 2*H*K + 1

struct TFPair { uint32_t a, b; };

__host__ __device__ constexpr uint32_t rotl32(uint32_t x, int r) {
  return (x << r) | (x >> (32 - r));
}

__host__ __device__ constexpr TFPair tf2x32(uint32_t k0, uint32_t k1,
                                            uint32_t x0, uint32_t x1) {
  uint32_t ks0 = k0, ks1 = k1, ks2 = k0 ^ k1 ^ 0x1BD11BDAu;
  x0 += ks0; x1 += ks1;
  x0 += x1; x1 = rotl32(x1, 13); x1 ^= x0;
  x0 += x1; x1 = rotl32(x1, 15); x1 ^= x0;
  x0 += x1; x1 = rotl32(x1, 26); x1 ^= x0;
  x0 += x1; x1 = rotl32(x1,  6); x1 ^= x0;
  x0 += ks1; x1 += ks2 + 1u;
  x0 += x1; x1 = rotl32(x1, 17); x1 ^= x0;
  x0 += x1; x1 = rotl32(x1, 29); x1 ^= x0;
  x0 += x1; x1 = rotl32(x1, 16); x1 ^= x0;
  x0 += x1; x1 = rotl32(x1, 24); x1 ^= x0;
  x0 += ks2; x1 += ks0 + 2u;
  x0 += x1; x1 = rotl32(x1, 13); x1 ^= x0;
  x0 += x1; x1 = rotl32(x1, 15); x1 ^= x0;
  x0 += x1; x1 = rotl32(x1, 26); x1 ^= x0;
  x0 += x1; x1 = rotl32(x1,  6); x1 ^= x0;
  x0 += ks0; x1 += ks1 + 3u;
  x0 += x1; x1 = rotl32(x1, 17); x1 ^= x0;
  x0 += x1; x1 = rotl32(x1, 29); x1 ^= x0;
  x0 += x1; x1 = rotl32(x1, 16); x1 ^= x0;
  x0 += x1; x1 = rotl32(x1, 24); x1 ^= x0;
  x0 += ks1; x1 += ks2 + 4u;
  x0 += x1; x1 = rotl32(x1, 13); x1 ^= x0;
  x0 += x1; x1 = rotl32(x1, 15); x1 ^= x0;
  x0 += x1; x1 = rotl32(x1, 26); x1 ^= x0;
  x0 += x1; x1 = rotl32(x1,  6); x1 ^= x0;
  x0 += ks2; x1 += ks0 + 5u;
  return {x0, x1};
}

// ---- compile-time key derivation (jax.random.key(42) == (0,42)) -----------
constexpr TFPair KM = tf2x32(0u, 42u, 0u, 0u);   // kmask = split(key)[0]
constexpr TFPair KP = tf2x32(0u, 42u, 0u, 1u);   // kperm = split(key)[1]
constexpr TFPair C2 = tf2x32(KM.a, KM.b, 0u, 1u);   // k2 of split(kmask)
constexpr uint32_t KLO0 = C2.a, KLO1 = C2.b;
constexpr TFPair SB = tf2x32(KP.a, KP.b, 0u, 1u);   // subkey of split(kperm)
constexpr uint32_t KSUB0 = SB.a, KSUB1 = SB.b;

// ---- compile-time permutation: inv_perm[m] = stable rank of sortkey[m] ----
struct Keys { uint32_t v[NC]; };
constexpr Keys make_keys() {
  Keys k{};
  for (int i = 0; i < NC; ++i) {
    TFPair r = tf2x32(KSUB0, KSUB1, 0u, (uint32_t)i);
    k.v[i] = r.a ^ r.b;          // 32-bit random_bits, partitionable: hi^lo
  }
  return k;
}
constexpr Keys KEYS = make_keys();

#define PART_SZ 33
struct Part { int v[PART_SZ]; };
constexpr Part make_part(int lo) {
  Part p{};
  for (int m = lo; m < lo + PART_SZ && m < NC; ++m) {
    uint32_t km = KEYS.v[m];
    int rank = 0;
    for (int j = 0; j < NC; ++j) {
      uint32_t kj = KEYS.v[j];
      if (kj < km || (kj == km && j < m)) ++rank;
    }
    p.v[m - lo] = rank;
  }
  return p;
}
// 16 separate constexpr variables: each gets its own constexpr step budget.
constexpr Part PT0  = make_part(0),   PT1  = make_part(33),
               PT2  = make_part(66),  PT3  = make_part(99),
               PT4  = make_part(132), PT5  = make_part(165),
               PT6  = make_part(198), PT7  = make_part(231),
               PT8  = make_part(264), PT9  = make_part(297),
               PT10 = make_part(330), PT11 = make_part(363),
               PT12 = make_part(396), PT13 = make_part(429),
               PT14 = make_part(462), PT15 = make_part(495);

struct IPerm { int v[NC]; };
constexpr IPerm merge_parts() {
  IPerm r{};
  const Part* ps[16] = {&PT0, &PT1, &PT2,  &PT3,  &PT4,  &PT5,  &PT6,  &PT7,
                        &PT8, &PT9, &PT10, &PT11, &PT12, &PT13, &PT14, &PT15};
  for (int c = 0; c < 16; ++c)
    for (int i = 0; i < PART_SZ; ++i) {
      int m = c * PART_SZ + i;
      if (m < NC) r.v[m] = ps[c]->v[i];
    }
  return r;
}
constexpr IPerm IPERM = merge_parts();
__device__ __constant__ IPerm d_iperm = IPERM;

// ---- dist kernel: grid (128 t-blocks, 32 j-groups), block 256 = 16t x 16tp -
__global__ __launch_bounds__(256) void dist_kernel(
    const int* __restrict__ locations, const int* __restrict__ pos_idx,
    const float* __restrict__ norm, float* __restrict__ out) {
  const int jg = blockIdx.y;                             // 0..31, scalar
  const int t  = ((int)blockIdx.x << 4) | ((int)threadIdx.x >> 4);
  const int tp = (int)threadIdx.x & 15;

  const int   ori  = locations[pos_idx[t] * TP_ + tp];
  const float nm   = norm[t];
  const float nm16 = nm * 0.0625f;                       // exact (2^-4 scale)
  float* outb = out + ((size_t)t * (NC * TP_) + tp);

  // 'ori' channel: dist(ori,ori) = 0.9375*norm, written once (jg==0)
  if (jg == 0) outb[d_iperm.v[256] * TP_] = 0.9375f * nm;

  const int j0 = jg << 3;                                // 8 j per block
  const int h  = j0 >> 4;                                // block-uniform
  const int k0 = j0 & (K_ - 1);
  const uint32_t hbit  = 1u << h;
  const uint32_t hmask = hbit - 1u;
  // flat index into (H, T, K, TP) mask tensor, chain jj adds jj*TP_
  const uint32_t idx0 = (uint32_t)(((h * T_ + t) * K_ + k0) * TP_ + tp);
  const uint32_t ao = (uint32_t)(ori < 0 ? -ori : ori);  // loop-invariant

#pragma unroll
  for (int jj = 0; jj < 8; ++jj) {
    const TFPair r = tf2x32(KLO0, KLO1, 0u, idx0 + (uint32_t)(jj * TP_));
    // flip bit h, xor the (2^h-1)-masked random bits
    const uint32_t fm = hbit ^ (r.b & hmask);
    const int v = ori ^ (int)fm;                         // sign(v)==sign(ori)
    const uint32_t av = (uint32_t)(v < 0 ? -v : v);
    const uint32_t x  = (av ^ ao) + 1u;                  // in [1, 2^16]
    const int lz = __clz((int)x);                        // e = 32 - lz
    // (1 - e/16)*nm == fma(lz, nm/16, -nm), single rounding == reference
    const float d1 = __builtin_fmaf((float)lz, nm16, -nm);
    const float d2 = (v == 0) ? d1 : -d1;                // dist(-v, ori)

    outb[d_iperm.v[j0 + jj]       * TP_] = d1;
    outb[d_iperm.v[j0 + jj + 257] * TP_] = d2;
  }
}

extern "C" void kernel_launch(void* const* d_in, const int* in_sizes, int n_in,
                              void* d_out, int out_size, void* d_ws, size_t ws_size,
                              hipStream_t stream) {
  const int*   locations = (const int*)d_in[0];
  const int*   pos_idx   = (const int*)d_in[1];
  const float* norm      = (const float*)d_in[2];
  float* out = (float*)d_out;

  hipLaunchKernelGGL(dist_kernel, dim3(128, 32), dim3(256), 0, stream,
                     locations, pos_idx, norm, out);
}